// Round 1
// baseline (1428.515 us; speedup 1.0000x reference)
//
#include <hip/hip_runtime.h>
#include <math.h>

#define NN 40000
#define NE 640000
#define NG 64
#define DINV 64
#define HDV 128
#define DEV 16
#define EF (NE + NN)

// ---------------- CSR construction ----------------

__global__ void k_count(const int* __restrict__ dst, int* __restrict__ cnt) {
    int e = blockIdx.x * 256 + threadIdx.x;
    if (e < NE) atomicAdd(&cnt[dst[e]], 1);
}

__global__ __launch_bounds__(1024) void k_scan(const int* __restrict__ cnt, int* __restrict__ rowptr) {
    const int C = 40;  // 1024*40 >= 40000
    int t = threadIdx.x;
    int start = t * C;
    int end = min(start + C, NN);
    int local = 0;
    for (int i = start; i < end; ++i) local += cnt[i] + 1;  // +1 self loop
    __shared__ int ssum[1024];
    ssum[t] = local;
    __syncthreads();
    for (int off = 1; off < 1024; off <<= 1) {
        int v = (t >= off) ? ssum[t - off] : 0;
        __syncthreads();
        ssum[t] += v;
        __syncthreads();
    }
    int running = (t == 0) ? 0 : ssum[t - 1];
    for (int i = start; i < end; ++i) {
        rowptr[i] = running;
        running += cnt[i] + 1;
    }
    if (end == NN && start < NN) rowptr[NN] = running;
}

__global__ void k_csr_init(const int* __restrict__ rowptr, int* __restrict__ cursor,
                           int* __restrict__ csr_src, int* __restrict__ csr_eid) {
    int n = blockIdx.x * 256 + threadIdx.x;
    if (n < NN) {
        cursor[n] = rowptr[n];
        int p = rowptr[n + 1] - 1;   // self-loop in last slot
        csr_src[p] = n;
        csr_eid[p] = NE + n;
    }
}

__global__ void k_fill(const int* __restrict__ src, const int* __restrict__ dst,
                       int* __restrict__ cursor, int* __restrict__ csr_src, int* __restrict__ csr_eid) {
    int e = blockIdx.x * 256 + threadIdx.x;
    if (e < NE) {
        int d = dst[e];
        int p = atomicAdd(&cursor[d], 1);
        csr_src[p] = src[e];
        csr_eid[p] = e;
    }
}

// loop_attr[n] = mean over incoming original edges' attrs (0 if none)
__global__ void k_loop_attr(const int* __restrict__ rowptr, const int* __restrict__ csr_eid,
                            const float* __restrict__ edge_attr, float* __restrict__ loop_attr) {
    int tid = blockIdx.x * 256 + threadIdx.x;
    int n = tid >> 4, k = tid & 15;
    if (n >= NN) return;
    int s = rowptr[n], e = rowptr[n + 1] - 1;  // exclude self loop slot
    float acc = 0.f;
    for (int i = s; i < e; ++i) acc += edge_attr[csr_eid[i] * DEV + k];
    int deg = e - s;
    loop_attr[n * DEV + k] = acc / (float)max(deg, 1);
}

// ---------------- dense transforms: XL = A@Wl, XR = A@Wr ----------------
// A: [NN, K] f32, Wl/Wr: [K, 128]. grid (625, 4), block 256.
__global__ __launch_bounds__(256) void k_gemm(const float* __restrict__ A, int K,
                                              const float* __restrict__ Wl, const float* __restrict__ Wr,
                                              float* __restrict__ XL, float* __restrict__ XR) {
    __shared__ float As[16][64];
    __shared__ float Bs[16][64];
    int t = threadIdx.x;
    int rb = blockIdx.x * 64;
    int by = blockIdx.y;
    const float* __restrict__ Bg = (by < 2) ? Wl : Wr;
    float* __restrict__ Xout = (by < 2) ? XL : XR;
    int colbase = (by & 1) * 64;
    int tx = t & 15, ty = t >> 4;
    float acc[4][4] = {};
    for (int k0 = 0; k0 < K; k0 += 16) {
        {   // A tile: 64 rows x 16 k
            int idx = t * 4;
            int row = idx >> 4;
            int kk = idx & 15;
            float4 v = *(const float4*)&A[(size_t)(rb + row) * K + k0 + kk];
            As[kk + 0][row] = v.x; As[kk + 1][row] = v.y; As[kk + 2][row] = v.z; As[kk + 3][row] = v.w;
        }
        {   // B tile: 16 k x 64 cols
            int idx = t * 4;
            int n = idx & 63, kk = idx >> 6;
            float4 v = *(const float4*)&Bg[(size_t)(k0 + kk) * HDV + colbase + n];
            *(float4*)&Bs[kk][n] = v;
        }
        __syncthreads();
        #pragma unroll
        for (int kk = 0; kk < 16; ++kk) {
            float4 a4 = *(const float4*)&As[kk][ty * 4];
            float4 b4 = *(const float4*)&Bs[kk][tx * 4];
            float ar[4] = {a4.x, a4.y, a4.z, a4.w};
            float br[4] = {b4.x, b4.y, b4.z, b4.w};
            #pragma unroll
            for (int i = 0; i < 4; ++i)
                #pragma unroll
                for (int j = 0; j < 4; ++j) acc[i][j] += ar[i] * br[j];
        }
        __syncthreads();
    }
    #pragma unroll
    for (int i = 0; i < 4; ++i) {
        int row = rb + ty * 4 + i;
        float4 v = {acc[i][0], acc[i][1], acc[i][2], acc[i][3]};
        *(float4*)&Xout[(size_t)row * HDV + colbase + tx * 4] = v;
    }
}

// ---------------- GATv2 per-node online-softmax aggregation ----------------
// one wave per node; lane L owns channels L (head0) and 64+L (head1)
__global__ __launch_bounds__(256) void k_gat(const float* __restrict__ XL, const float* __restrict__ XR,
                                             const int* __restrict__ rowptr, const int* __restrict__ csr_src,
                                             const int* __restrict__ csr_eid,
                                             const float* __restrict__ edge_attr, const float* __restrict__ loop_attr,
                                             const float* __restrict__ we, const float* __restrict__ att,
                                             const float* __restrict__ cb, float* __restrict__ hpre) {
    __shared__ float lwe[DEV * HDV];  // 8 KB
    int t = threadIdx.x;
    for (int i = t; i < DEV * HDV; i += 256) lwe[i] = we[i];
    __syncthreads();
    int wid = t >> 6, L = t & 63;
    int d = blockIdx.x * 4 + wid;
    if (d >= NN) return;
    float attv0 = att[L], attv1 = att[64 + L];
    float xr0 = XR[(size_t)d * HDV + L];
    float xr1 = XR[(size_t)d * HDV + 64 + L];
    int istart = rowptr[d], iend = rowptr[d + 1];
    float M0 = -1e30f, M1 = -1e30f;
    float D0 = 0.f, D1 = 0.f, acc0 = 0.f, acc1 = 0.f;
    for (int i = istart; i < iend; ++i) {
        int s = csr_src[i];
        int eid = csr_eid[i];
        float xl0 = XL[(size_t)s * HDV + L];
        float xl1 = XL[(size_t)s * HDV + 64 + L];
        const float* eap = (eid < NE) ? &edge_attr[(size_t)eid * DEV]
                                      : &loop_attr[(size_t)(eid - NE) * DEV];
        float eav = eap[L & 15];
        float ee0 = 0.f, ee1 = 0.f;
        #pragma unroll
        for (int k = 0; k < DEV; ++k) {
            float ek = __shfl(eav, k, 64);
            ee0 += ek * lwe[k * HDV + L];
            ee1 += ek * lwe[k * HDV + 64 + L];
        }
        float m0 = xl0 + xr0 + ee0;
        float m1 = xl1 + xr1 + ee1;
        float c0 = (m0 > 0.f ? m0 : 0.2f * m0) * attv0;
        float c1 = (m1 > 0.f ? m1 : 0.2f * m1) * attv1;
        #pragma unroll
        for (int off = 32; off > 0; off >>= 1) {
            c0 += __shfl_xor(c0, off, 64);
            c1 += __shfl_xor(c1, off, 64);
        }
        float nm0 = fmaxf(M0, c0), nm1 = fmaxf(M1, c1);
        float scale0 = expf(M0 - nm0), scale1 = expf(M1 - nm1);
        float e0 = expf(c0 - nm0), e1 = expf(c1 - nm1);
        D0 = D0 * scale0 + e0;
        D1 = D1 * scale1 + e1;
        acc0 = acc0 * scale0 + e0 * xl0;
        acc1 = acc1 * scale1 + e1 * xl1;
        M0 = nm0; M1 = nm1;
    }
    hpre[(size_t)d * HDV + L]      = acc0 / (D0 + 1e-16f) + cb[L];
    hpre[(size_t)d * HDV + 64 + L] = acc1 / (D1 + 1e-16f) + cb[64 + L];
}

// ---------------- BatchNorm ----------------

__global__ __launch_bounds__(256) void k_bn_stats(const float* __restrict__ hpre,
                                                  double* __restrict__ bnsum, double* __restrict__ bnsumsq) {
    int c = threadIdx.x & 127, half = threadIdx.x >> 7;
    int r0 = blockIdx.x * 250;
    double s = 0.0, q = 0.0;
    for (int r = r0 + half; r < r0 + 250; r += 2) {
        float v = hpre[(size_t)r * HDV + c];
        s += v;
        q += (double)v * (double)v;
    }
    __shared__ double ls[256], lq[256];
    ls[threadIdx.x] = s; lq[threadIdx.x] = q;
    __syncthreads();
    if (half == 0) {
        s += ls[threadIdx.x + 128];
        q += lq[threadIdx.x + 128];
        atomicAdd(&bnsum[c], s);
        atomicAdd(&bnsumsq[c], q);
    }
}

__global__ __launch_bounds__(256) void k_bn_apply(const float* __restrict__ hpre,
                                                  const double* __restrict__ bnsum, const double* __restrict__ bnsumsq,
                                                  const float* __restrict__ g, const float* __restrict__ bb,
                                                  float* __restrict__ act) {
    int idx = (blockIdx.x * 256 + threadIdx.x) * 4;
    if (idx >= NN * HDV) return;
    int c = idx & 127;
    float4 h = *(const float4*)&hpre[idx];
    float hv[4] = {h.x, h.y, h.z, h.w};
    float o[4];
    #pragma unroll
    for (int j = 0; j < 4; ++j) {
        int cc = c + j;
        double mu = bnsum[cc] * (1.0 / NN);
        double var = bnsumsq[cc] * (1.0 / NN) - mu * mu;
        float inv = (float)rsqrt(var + 1e-5);
        float xv = (hv[j] - (float)mu) * inv * g[cc] + bb[cc];
        o[j] = xv > 0.f ? xv : 0.01f * xv;
    }
    float4 v = {o[0], o[1], o[2], o[3]};
    *(float4*)&act[idx] = v;
}

// ---------------- pooling + MLP ----------------

__global__ void k_pool(const float* __restrict__ act, const int* __restrict__ batch,
                       float* __restrict__ pooled_sum, int* __restrict__ gcnt) {
    int idx = blockIdx.x * 256 + threadIdx.x;
    if (idx >= NN * HDV) return;
    int n = idx >> 7, c = idx & 127;
    int b = batch[n];
    atomicAdd(&pooled_sum[b * HDV + c], act[idx]);
    if (c == 0) atomicAdd(&gcnt[b], 1);
}

__global__ __launch_bounds__(512) void k_mlp(const float* __restrict__ pooled_sum, const int* __restrict__ gcnt,
                                             const float* __restrict__ fc1w, const float* __restrict__ fc1b,
                                             const float* __restrict__ fc2w, const float* __restrict__ fc2b,
                                             float* __restrict__ out) {
    __shared__ float pl[NG * HDV];   // 32 KB
    __shared__ float hh[NG * 64];    // 16 KB
    int t = threadIdx.x;
    for (int i = t; i < NG * HDV; i += 512) {
        int g = i >> 7;
        int cnt = max(gcnt[g], 1);
        pl[i] = pooled_sum[i] / (float)cnt;
    }
    __syncthreads();
    for (int i = t; i < NG * 64; i += 512) {
        int g = i >> 6, c = i & 63;
        float s = fc1b[c];
        for (int k = 0; k < HDV; ++k) s += pl[g * HDV + k] * fc1w[k * 64 + c];
        hh[i] = s > 0.f ? s : 0.f;
    }
    __syncthreads();
    if (t < NG) {
        float s = fc2b[0];
        for (int k = 0; k < 64; ++k) s += hh[t * 64 + k] * fc2w[k];
        out[t] = s;
    }
}

// ---------------- launch ----------------

extern "C" void kernel_launch(void* const* d_in, const int* in_sizes, int n_in,
                              void* d_out, int out_size, void* d_ws, size_t ws_size,
                              hipStream_t stream) {
    const float* x = (const float*)d_in[0];
    const int* ei = (const int*)d_in[1];
    const int* src = ei;
    const int* dst = ei + NE;
    const float* ea = (const float*)d_in[2];
    const int* batch = (const int*)d_in[3];
    const float* fc1w = (const float*)d_in[25];
    const float* fc1b = (const float*)d_in[26];
    const float* fc2w = (const float*)d_in[27];
    const float* fc2b = (const float*)d_in[28];
    float* out = (float*)d_out;

    char* ws = (char*)d_ws;
    size_t off = 0;
    auto alloc = [&](size_t bytes) -> void* {
        void* p = ws + off;
        off = (off + bytes + 255) & ~(size_t)255;
        return p;
    };

    // zero region (memset every launch)
    int* cnt = (int*)alloc(NN * 4);
    int* gcnt = (int*)alloc(NG * 4);
    float* pooled_sum = (float*)alloc(NG * HDV * 4);
    double* bnsum = (double*)alloc(3 * HDV * 8);
    double* bnsumsq = (double*)alloc(3 * HDV * 8);
    size_t zero_bytes = off;

    int* rowptr = (int*)alloc((NN + 1) * 4);
    int* cursor = (int*)alloc(NN * 4);
    int* csr_src = (int*)alloc((size_t)EF * 4);
    int* csr_eid = (int*)alloc((size_t)EF * 4);
    float* loop_attr = (float*)alloc((size_t)NN * DEV * 4);
    float* XLb = (float*)alloc((size_t)NN * HDV * 4);
    float* XRb = (float*)alloc((size_t)NN * HDV * 4);
    float* hpre = (float*)alloc((size_t)NN * HDV * 4);
    float* actb = (float*)alloc((size_t)NN * HDV * 4);
    (void)ws_size; (void)in_sizes; (void)n_in; (void)out_size;

    hipMemsetAsync(d_ws, 0, zero_bytes, stream);

    k_count<<<(NE + 255) / 256, 256, 0, stream>>>(dst, cnt);
    k_scan<<<1, 1024, 0, stream>>>(cnt, rowptr);
    k_csr_init<<<(NN + 255) / 256, 256, 0, stream>>>(rowptr, cursor, csr_src, csr_eid);
    k_fill<<<(NE + 255) / 256, 256, 0, stream>>>(src, dst, cursor, csr_src, csr_eid);
    k_loop_attr<<<(NN * DEV + 255) / 256, 256, 0, stream>>>(rowptr, csr_eid, ea, loop_attr);

    const float* actp = x;
    int K = DINV;
    for (int L = 0; L < 3; ++L) {
        const float* wl = (const float*)d_in[4 + 7 * L + 0];
        const float* wr = (const float*)d_in[4 + 7 * L + 1];
        const float* we = (const float*)d_in[4 + 7 * L + 2];
        const float* a  = (const float*)d_in[4 + 7 * L + 3];
        const float* cb = (const float*)d_in[4 + 7 * L + 4];
        const float* g  = (const float*)d_in[4 + 7 * L + 5];
        const float* bb = (const float*)d_in[4 + 7 * L + 6];

        k_gemm<<<dim3(NN / 64, 4), 256, 0, stream>>>(actp, K, wl, wr, XLb, XRb);
        k_gat<<<NN / 4, 256, 0, stream>>>(XLb, XRb, rowptr, csr_src, csr_eid, ea, loop_attr, we, a, cb, hpre);
        k_bn_stats<<<160, 256, 0, stream>>>(hpre, bnsum + (size_t)L * HDV, bnsumsq + (size_t)L * HDV);
        k_bn_apply<<<NN * HDV / 4 / 256, 256, 0, stream>>>(hpre, bnsum + (size_t)L * HDV, bnsumsq + (size_t)L * HDV, g, bb, actb);
        actp = actb;
        K = HDV;
    }

    k_pool<<<NN * HDV / 256, 256, 0, stream>>>(actb, batch, pooled_sum, gcnt);
    k_mlp<<<1, 512, 0, stream>>>(pooled_sum, gcnt, fc1w, fc1b, fc2w, fc2b, out);
}

// Round 2
// 1206.956 us; speedup vs baseline: 1.1836x; 1.1836x over previous
//
#include <hip/hip_runtime.h>
#include <math.h>

#define NN 40000
#define NE 640000
#define NG 64
#define DINV 64
#define HDV 128
#define DEV 16
#define EF (NE + NN)

// ---------------- CSR construction ----------------

__global__ void k_count(const int* __restrict__ dst, int* __restrict__ cnt) {
    int e = blockIdx.x * 256 + threadIdx.x;
    if (e < NE) atomicAdd(&cnt[dst[e]], 1);
}

__global__ __launch_bounds__(1024) void k_scan(const int* __restrict__ cnt, int* __restrict__ rowptr) {
    const int C = 40;  // 1024*40 >= 40000
    int t = threadIdx.x;
    int start = t * C;
    int end = min(start + C, NN);
    int local = 0;
    for (int i = start; i < end; ++i) local += cnt[i] + 1;  // +1 self loop
    __shared__ int ssum[1024];
    ssum[t] = local;
    __syncthreads();
    for (int off = 1; off < 1024; off <<= 1) {
        int v = (t >= off) ? ssum[t - off] : 0;
        __syncthreads();
        ssum[t] += v;
        __syncthreads();
    }
    int running = (t == 0) ? 0 : ssum[t - 1];
    for (int i = start; i < end; ++i) {
        rowptr[i] = running;
        running += cnt[i] + 1;
    }
    if (end == NN && start < NN) rowptr[NN] = running;
}

__global__ void k_csr_init(const int* __restrict__ rowptr, int* __restrict__ cursor,
                           int* __restrict__ csr_src, int* __restrict__ csr_eid) {
    int n = blockIdx.x * 256 + threadIdx.x;
    if (n < NN) {
        cursor[n] = rowptr[n];
        int p = rowptr[n + 1] - 1;   // self-loop in last slot
        csr_src[p] = n;
        csr_eid[p] = NE + n;
    }
}

__global__ void k_fill(const int* __restrict__ src, const int* __restrict__ dst,
                       int* __restrict__ cursor, int* __restrict__ csr_src, int* __restrict__ csr_eid) {
    int e = blockIdx.x * 256 + threadIdx.x;
    if (e < NE) {
        int d = dst[e];
        int p = atomicAdd(&cursor[d], 1);
        csr_src[p] = src[e];
        csr_eid[p] = e;
    }
}

// loop_attr[n] = mean over incoming original edges' attrs (0 if none)
__global__ void k_loop_attr(const int* __restrict__ rowptr, const int* __restrict__ csr_eid,
                            const float* __restrict__ edge_attr, float* __restrict__ loop_attr) {
    int tid = blockIdx.x * 256 + threadIdx.x;
    int n = tid >> 4, k = tid & 15;
    if (n >= NN) return;
    int s = rowptr[n], e = rowptr[n + 1] - 1;  // exclude self loop slot
    float acc = 0.f;
    for (int i = s; i < e; ++i) acc += edge_attr[csr_eid[i] * DEV + k];
    int deg = e - s;
    loop_attr[n * DEV + k] = acc / (float)max(deg, 1);
}

// ---------------- dense transforms: XL = A@Wl, XR = A@Wr ----------------
// A: [NN, K] f32, Wl/Wr: [K, 128]. grid (625, 4), block 256.
__global__ __launch_bounds__(256) void k_gemm(const float* __restrict__ A, int K,
                                              const float* __restrict__ Wl, const float* __restrict__ Wr,
                                              float* __restrict__ XL, float* __restrict__ XR) {
    __shared__ float As[16][64];
    __shared__ float Bs[16][64];
    int t = threadIdx.x;
    int rb = blockIdx.x * 64;
    int by = blockIdx.y;
    const float* __restrict__ Bg = (by < 2) ? Wl : Wr;
    float* __restrict__ Xout = (by < 2) ? XL : XR;
    int colbase = (by & 1) * 64;
    int tx = t & 15, ty = t >> 4;
    float acc[4][4] = {};
    for (int k0 = 0; k0 < K; k0 += 16) {
        {   // A tile: 64 rows x 16 k
            int idx = t * 4;
            int row = idx >> 4;
            int kk = idx & 15;
            float4 v = *(const float4*)&A[(size_t)(rb + row) * K + k0 + kk];
            As[kk + 0][row] = v.x; As[kk + 1][row] = v.y; As[kk + 2][row] = v.z; As[kk + 3][row] = v.w;
        }
        {   // B tile: 16 k x 64 cols
            int idx = t * 4;
            int n = idx & 63, kk = idx >> 6;
            float4 v = *(const float4*)&Bg[(size_t)(k0 + kk) * HDV + colbase + n];
            *(float4*)&Bs[kk][n] = v;
        }
        __syncthreads();
        #pragma unroll
        for (int kk = 0; kk < 16; ++kk) {
            float4 a4 = *(const float4*)&As[kk][ty * 4];
            float4 b4 = *(const float4*)&Bs[kk][tx * 4];
            float ar[4] = {a4.x, a4.y, a4.z, a4.w};
            float br[4] = {b4.x, b4.y, b4.z, b4.w};
            #pragma unroll
            for (int i = 0; i < 4; ++i)
                #pragma unroll
                for (int j = 0; j < 4; ++j) acc[i][j] += ar[i] * br[j];
        }
        __syncthreads();
    }
    #pragma unroll
    for (int i = 0; i < 4; ++i) {
        int row = rb + ty * 4 + i;
        float4 v = {acc[i][0], acc[i][1], acc[i][2], acc[i][3]};
        *(float4*)&Xout[(size_t)row * HDV + colbase + tx * 4] = v;
    }
}

// ---------------- GATv2 per-node online-softmax aggregation ----------------
// one wave per node; lane L owns channels L (head0) and 64+L (head1)
__global__ __launch_bounds__(256) void k_gat(const float* __restrict__ XL, const float* __restrict__ XR,
                                             const int* __restrict__ rowptr, const int* __restrict__ csr_src,
                                             const int* __restrict__ csr_eid,
                                             const float* __restrict__ edge_attr, const float* __restrict__ loop_attr,
                                             const float* __restrict__ we, const float* __restrict__ att,
                                             const float* __restrict__ cb, float* __restrict__ hpre) {
    __shared__ float lwe[DEV * HDV];  // 8 KB
    int t = threadIdx.x;
    for (int i = t; i < DEV * HDV; i += 256) lwe[i] = we[i];
    __syncthreads();
    int wid = t >> 6, L = t & 63;
    int d = blockIdx.x * 4 + wid;
    if (d >= NN) return;
    float attv0 = att[L], attv1 = att[64 + L];
    float xr0 = XR[(size_t)d * HDV + L];
    float xr1 = XR[(size_t)d * HDV + 64 + L];
    int istart = rowptr[d], iend = rowptr[d + 1];
    float M0 = -1e30f, M1 = -1e30f;
    float D0 = 0.f, D1 = 0.f, acc0 = 0.f, acc1 = 0.f;
    for (int i = istart; i < iend; ++i) {
        int s = csr_src[i];
        int eid = csr_eid[i];
        float xl0 = XL[(size_t)s * HDV + L];
        float xl1 = XL[(size_t)s * HDV + 64 + L];
        const float* eap = (eid < NE) ? &edge_attr[(size_t)eid * DEV]
                                      : &loop_attr[(size_t)(eid - NE) * DEV];
        float eav = eap[L & 15];
        float ee0 = 0.f, ee1 = 0.f;
        #pragma unroll
        for (int k = 0; k < DEV; ++k) {
            float ek = __shfl(eav, k, 64);
            ee0 += ek * lwe[k * HDV + L];
            ee1 += ek * lwe[k * HDV + 64 + L];
        }
        float m0 = xl0 + xr0 + ee0;
        float m1 = xl1 + xr1 + ee1;
        float c0 = (m0 > 0.f ? m0 : 0.2f * m0) * attv0;
        float c1 = (m1 > 0.f ? m1 : 0.2f * m1) * attv1;
        #pragma unroll
        for (int off = 32; off > 0; off >>= 1) {
            c0 += __shfl_xor(c0, off, 64);
            c1 += __shfl_xor(c1, off, 64);
        }
        float nm0 = fmaxf(M0, c0), nm1 = fmaxf(M1, c1);
        float scale0 = expf(M0 - nm0), scale1 = expf(M1 - nm1);
        float e0 = expf(c0 - nm0), e1 = expf(c1 - nm1);
        D0 = D0 * scale0 + e0;
        D1 = D1 * scale1 + e1;
        acc0 = acc0 * scale0 + e0 * xl0;
        acc1 = acc1 * scale1 + e1 * xl1;
        M0 = nm0; M1 = nm1;
    }
    hpre[(size_t)d * HDV + L]      = acc0 / (D0 + 1e-16f) + cb[L];
    hpre[(size_t)d * HDV + 64 + L] = acc1 / (D1 + 1e-16f) + cb[64 + L];
}

// ---------------- BatchNorm ----------------

__global__ __launch_bounds__(256) void k_bn_stats(const float* __restrict__ hpre,
                                                  double* __restrict__ bnsum, double* __restrict__ bnsumsq) {
    int c = threadIdx.x & 127, half = threadIdx.x >> 7;
    int r0 = blockIdx.x * 250;
    double s = 0.0, q = 0.0;
    for (int r = r0 + half; r < r0 + 250; r += 2) {
        float v = hpre[(size_t)r * HDV + c];
        s += v;
        q += (double)v * (double)v;
    }
    __shared__ double ls[256], lq[256];
    ls[threadIdx.x] = s; lq[threadIdx.x] = q;
    __syncthreads();
    if (half == 0) {
        s += ls[threadIdx.x + 128];
        q += lq[threadIdx.x + 128];
        atomicAdd(&bnsum[c], s);
        atomicAdd(&bnsumsq[c], q);
    }
}

__global__ __launch_bounds__(256) void k_bn_apply(const float* __restrict__ hpre,
                                                  const double* __restrict__ bnsum, const double* __restrict__ bnsumsq,
                                                  const float* __restrict__ g, const float* __restrict__ bb,
                                                  float* __restrict__ act) {
    int idx = (blockIdx.x * 256 + threadIdx.x) * 4;
    if (idx >= NN * HDV) return;
    int c = idx & 127;
    float4 h = *(const float4*)&hpre[idx];
    float hv[4] = {h.x, h.y, h.z, h.w};
    float o[4];
    #pragma unroll
    for (int j = 0; j < 4; ++j) {
        int cc = c + j;
        double mu = bnsum[cc] * (1.0 / NN);
        double var = bnsumsq[cc] * (1.0 / NN) - mu * mu;
        float inv = (float)rsqrt(var + 1e-5);
        float xv = (hv[j] - (float)mu) * inv * g[cc] + bb[cc];
        o[j] = xv > 0.f ? xv : 0.01f * xv;
    }
    float4 v = {o[0], o[1], o[2], o[3]};
    *(float4*)&act[idx] = v;
}

// ---------------- pooling + MLP ----------------

// batch is sorted: binary-search graph boundaries. gstart[NG] = NN.
__global__ void k_gbounds(const int* __restrict__ batch, int* __restrict__ gstart) {
    int g = threadIdx.x;
    if (g > NG) return;
    int lo = 0, hi = NN;
    while (lo < hi) {
        int mid = (lo + hi) >> 1;
        if (batch[mid] < g) lo = mid + 1; else hi = mid;
    }
    gstart[g] = lo;
}

// one block per graph: streaming reduction, no atomics; writes pooled MEAN
__global__ __launch_bounds__(256) void k_pool2(const float* __restrict__ act, const int* __restrict__ gstart,
                                               float* __restrict__ pooled) {
    int g = blockIdx.x;
    int s = gstart[g], e = gstart[g + 1];
    int c = threadIdx.x & 127, half = threadIdx.x >> 7;
    float acc = 0.f;
    for (int r = s + half; r < e; r += 2) acc += act[(size_t)r * HDV + c];
    __shared__ float ls[256];
    ls[threadIdx.x] = acc;
    __syncthreads();
    if (half == 0) {
        float v = acc + ls[threadIdx.x + 128];
        int cntn = e - s;
        pooled[g * HDV + c] = v / (float)max(cntn, 1);
    }
}

__global__ __launch_bounds__(512) void k_mlp(const float* __restrict__ pooled,
                                             const float* __restrict__ fc1w, const float* __restrict__ fc1b,
                                             const float* __restrict__ fc2w, const float* __restrict__ fc2b,
                                             float* __restrict__ out) {
    __shared__ float pl[NG * HDV];   // 32 KB
    __shared__ float hh[NG * 64];    // 16 KB
    int t = threadIdx.x;
    for (int i = t; i < NG * HDV; i += 512) pl[i] = pooled[i];
    __syncthreads();
    for (int i = t; i < NG * 64; i += 512) {
        int g = i >> 6, c = i & 63;
        float s = fc1b[c];
        for (int k = 0; k < HDV; ++k) s += pl[g * HDV + k] * fc1w[k * 64 + c];
        hh[i] = s > 0.f ? s : 0.f;
    }
    __syncthreads();
    if (t < NG) {
        float s = fc2b[0];
        for (int k = 0; k < 64; ++k) s += hh[t * 64 + k] * fc2w[k];
        out[t] = s;
    }
}

// ---------------- launch ----------------

extern "C" void kernel_launch(void* const* d_in, const int* in_sizes, int n_in,
                              void* d_out, int out_size, void* d_ws, size_t ws_size,
                              hipStream_t stream) {
    const float* x = (const float*)d_in[0];
    const int* ei = (const int*)d_in[1];
    const int* src = ei;
    const int* dst = ei + NE;
    const float* ea = (const float*)d_in[2];
    const int* batch = (const int*)d_in[3];
    const float* fc1w = (const float*)d_in[25];
    const float* fc1b = (const float*)d_in[26];
    const float* fc2w = (const float*)d_in[27];
    const float* fc2b = (const float*)d_in[28];
    float* out = (float*)d_out;

    char* ws = (char*)d_ws;
    size_t off = 0;
    auto alloc = [&](size_t bytes) -> void* {
        void* p = ws + off;
        off = (off + bytes + 255) & ~(size_t)255;
        return p;
    };

    // zero region (memset every launch)
    int* cnt = (int*)alloc(NN * 4);
    double* bnsum = (double*)alloc(3 * HDV * 8);
    double* bnsumsq = (double*)alloc(3 * HDV * 8);
    size_t zero_bytes = off;

    int* rowptr = (int*)alloc((NN + 1) * 4);
    int* cursor = (int*)alloc(NN * 4);
    int* gstart = (int*)alloc((NG + 1) * 4);
    float* pooled = (float*)alloc(NG * HDV * 4);
    int* csr_src = (int*)alloc((size_t)EF * 4);
    int* csr_eid = (int*)alloc((size_t)EF * 4);
    float* loop_attr = (float*)alloc((size_t)NN * DEV * 4);
    float* XLb = (float*)alloc((size_t)NN * HDV * 4);
    float* XRb = (float*)alloc((size_t)NN * HDV * 4);
    float* hpre = (float*)alloc((size_t)NN * HDV * 4);
    float* actb = (float*)alloc((size_t)NN * HDV * 4);
    (void)ws_size; (void)in_sizes; (void)n_in; (void)out_size;

    hipMemsetAsync(d_ws, 0, zero_bytes, stream);

    k_count<<<(NE + 255) / 256, 256, 0, stream>>>(dst, cnt);
    k_scan<<<1, 1024, 0, stream>>>(cnt, rowptr);
    k_csr_init<<<(NN + 255) / 256, 256, 0, stream>>>(rowptr, cursor, csr_src, csr_eid);
    k_fill<<<(NE + 255) / 256, 256, 0, stream>>>(src, dst, cursor, csr_src, csr_eid);
    k_loop_attr<<<(NN * DEV + 255) / 256, 256, 0, stream>>>(rowptr, csr_eid, ea, loop_attr);
    k_gbounds<<<1, 128, 0, stream>>>(batch, gstart);

    const float* actp = x;
    int K = DINV;
    for (int L = 0; L < 3; ++L) {
        const float* wl = (const float*)d_in[4 + 7 * L + 0];
        const float* wr = (const float*)d_in[4 + 7 * L + 1];
        const float* we = (const float*)d_in[4 + 7 * L + 2];
        const float* a  = (const float*)d_in[4 + 7 * L + 3];
        const float* cb = (const float*)d_in[4 + 7 * L + 4];
        const float* g  = (const float*)d_in[4 + 7 * L + 5];
        const float* bb = (const float*)d_in[4 + 7 * L + 6];

        k_gemm<<<dim3(NN / 64, 4), 256, 0, stream>>>(actp, K, wl, wr, XLb, XRb);
        k_gat<<<NN / 4, 256, 0, stream>>>(XLb, XRb, rowptr, csr_src, csr_eid, ea, loop_attr, we, a, cb, hpre);
        k_bn_stats<<<160, 256, 0, stream>>>(hpre, bnsum + (size_t)L * HDV, bnsumsq + (size_t)L * HDV);
        k_bn_apply<<<NN * HDV / 4 / 256, 256, 0, stream>>>(hpre, bnsum + (size_t)L * HDV, bnsumsq + (size_t)L * HDV, g, bb, actb);
        actp = actb;
        K = HDV;
    }

    k_pool2<<<NG, 256, 0, stream>>>(actb, gstart, pooled);
    k_mlp<<<1, 512, 0, stream>>>(pooled, fc1w, fc1b, fc2w, fc2b, out);
}

// Round 3
// 844.711 us; speedup vs baseline: 1.6911x; 1.4288x over previous
//
#include <hip/hip_runtime.h>
#include <math.h>

#define NN 40000
#define NE 640000
#define NG 64
#define DINV 64
#define HDV 128
#define DEV 16
#define EF (NE + NN)

// ---------------- CSR construction ----------------

__global__ void k_count(const int* __restrict__ dst, int* __restrict__ cnt) {
    int e = blockIdx.x * 256 + threadIdx.x;
    if (e < NE) atomicAdd(&cnt[dst[e]], 1);
}

__global__ __launch_bounds__(1024) void k_scan(const int* __restrict__ cnt, int* __restrict__ rowptr) {
    const int C = 40;  // 1024*40 >= 40000
    int t = threadIdx.x;
    int start = t * C;
    int end = min(start + C, NN);
    int local = 0;
    for (int i = start; i < end; ++i) local += cnt[i] + 1;  // +1 self loop
    __shared__ int ssum[1024];
    ssum[t] = local;
    __syncthreads();
    for (int off = 1; off < 1024; off <<= 1) {
        int v = (t >= off) ? ssum[t - off] : 0;
        __syncthreads();
        ssum[t] += v;
        __syncthreads();
    }
    int running = (t == 0) ? 0 : ssum[t - 1];
    for (int i = start; i < end; ++i) {
        rowptr[i] = running;
        running += cnt[i] + 1;
    }
    if (end == NN && start < NN) rowptr[NN] = running;
}

__global__ void k_csr_init(const int* __restrict__ rowptr, int* __restrict__ cursor,
                           int* __restrict__ csr_src) {
    int n = blockIdx.x * 256 + threadIdx.x;
    if (n < NN) {
        cursor[n] = rowptr[n];
        csr_src[rowptr[n + 1] - 1] = n;   // self-loop in last slot
    }
}

// fill CSR adjacency AND edge attrs in CSR order
__global__ void k_fill(const int* __restrict__ src, const int* __restrict__ dst,
                       const float* __restrict__ edge_attr,
                       int* __restrict__ cursor, int* __restrict__ csr_src, float* __restrict__ csr_ea) {
    int e = blockIdx.x * 256 + threadIdx.x;
    if (e < NE) {
        int d = dst[e];
        int p = atomicAdd(&cursor[d], 1);
        csr_src[p] = src[e];
        const float4* s4 = (const float4*)&edge_attr[(size_t)e * DEV];
        float4* d4 = (float4*)&csr_ea[(size_t)p * DEV];
        d4[0] = s4[0]; d4[1] = s4[1]; d4[2] = s4[2]; d4[3] = s4[3];
    }
}

// self-loop attr = mean over incoming original edges' attrs (0 if none), written in place
__global__ void k_loop_attr(const int* __restrict__ rowptr, float* __restrict__ csr_ea) {
    int tid = blockIdx.x * 256 + threadIdx.x;
    int n = tid >> 4, k = tid & 15;
    if (n >= NN) return;
    int s = rowptr[n], e = rowptr[n + 1] - 1;  // exclude self loop slot
    float acc = 0.f;
    for (int i = s; i < e; ++i) acc += csr_ea[(size_t)i * DEV + k];
    csr_ea[(size_t)e * DEV + k] = acc / (float)max(e - s, 1);
}

// ---------------- dense transforms: XL = A@Wl, XR = A@Wr ----------------
__global__ __launch_bounds__(256) void k_gemm(const float* __restrict__ A, int K,
                                              const float* __restrict__ Wl, const float* __restrict__ Wr,
                                              float* __restrict__ XL, float* __restrict__ XR) {
    __shared__ float As[16][64];
    __shared__ float Bs[16][64];
    int t = threadIdx.x;
    int rb = blockIdx.x * 64;
    int by = blockIdx.y;
    const float* __restrict__ Bg = (by < 2) ? Wl : Wr;
    float* __restrict__ Xout = (by < 2) ? XL : XR;
    int colbase = (by & 1) * 64;
    int tx = t & 15, ty = t >> 4;
    float acc[4][4] = {};
    for (int k0 = 0; k0 < K; k0 += 16) {
        {   // A tile: 64 rows x 16 k
            int idx = t * 4;
            int row = idx >> 4;
            int kk = idx & 15;
            float4 v = *(const float4*)&A[(size_t)(rb + row) * K + k0 + kk];
            As[kk + 0][row] = v.x; As[kk + 1][row] = v.y; As[kk + 2][row] = v.z; As[kk + 3][row] = v.w;
        }
        {   // B tile: 16 k x 64 cols
            int idx = t * 4;
            int n = idx & 63, kk = idx >> 6;
            float4 v = *(const float4*)&Bg[(size_t)(k0 + kk) * HDV + colbase + n];
            *(float4*)&Bs[kk][n] = v;
        }
        __syncthreads();
        #pragma unroll
        for (int kk = 0; kk < 16; ++kk) {
            float4 a4 = *(const float4*)&As[kk][ty * 4];
            float4 b4 = *(const float4*)&Bs[kk][tx * 4];
            float ar[4] = {a4.x, a4.y, a4.z, a4.w};
            float br[4] = {b4.x, b4.y, b4.z, b4.w};
            #pragma unroll
            for (int i = 0; i < 4; ++i)
                #pragma unroll
                for (int j = 0; j < 4; ++j) acc[i][j] += ar[i] * br[j];
        }
        __syncthreads();
    }
    #pragma unroll
    for (int i = 0; i < 4; ++i) {
        int row = rb + ty * 4 + i;
        float4 v = {acc[i][0], acc[i][1], acc[i][2], acc[i][3]};
        *(float4*)&Xout[(size_t)row * HDV + colbase + tx * 4] = v;
    }
}

// ---------------- GATv2 per-node online-softmax aggregation ----------------
// one wave per node; lane L owns channels L (head0) and 64+L (head1).
// d is wave-uniform (readfirstlane) -> rowptr/csr_src/csr_ea become scalar loads.
__global__ __launch_bounds__(256) void k_gat(const float* __restrict__ XL, const float* __restrict__ XR,
                                             const int* __restrict__ rowptr, const int* __restrict__ csr_src,
                                             const float* __restrict__ csr_ea,
                                             const float* __restrict__ we, const float* __restrict__ att,
                                             const float* __restrict__ cb, float* __restrict__ hpre) {
    int t = threadIdx.x;
    int L = t & 63;
    int d = __builtin_amdgcn_readfirstlane(blockIdx.x * 4 + (t >> 6));
    // We in registers: 32 VGPRs
    float rwe0[DEV], rwe1[DEV];
    #pragma unroll
    for (int k = 0; k < DEV; ++k) {
        rwe0[k] = we[k * HDV + L];
        rwe1[k] = we[k * HDV + 64 + L];
    }
    float attv0 = att[L], attv1 = att[64 + L];
    float xr0 = XR[(size_t)d * HDV + L];
    float xr1 = XR[(size_t)d * HDV + 64 + L];
    int istart = rowptr[d], iend = rowptr[d + 1];
    float M0 = -1e30f, M1 = -1e30f;
    float D0 = 0.f, D1 = 0.f, acc0 = 0.f, acc1 = 0.f;
    for (int i = istart; i < iend; ++i) {
        int s = csr_src[i];                       // scalar load (uniform i)
        const float* eap = &csr_ea[(size_t)i * DEV];
        float xl0 = XL[(size_t)s * HDV + L];
        float xl1 = XL[(size_t)s * HDV + 64 + L];
        float ee0 = 0.f, ee1 = 0.f;
        #pragma unroll
        for (int k = 0; k < DEV; ++k) {
            float ek = eap[k];                    // s_load into SGPR
            ee0 = fmaf(ek, rwe0[k], ee0);
            ee1 = fmaf(ek, rwe1[k], ee1);
        }
        float m0 = xl0 + xr0 + ee0;
        float m1 = xl1 + xr1 + ee1;
        float c0 = fmaxf(m0, 0.2f * m0) * attv0;  // leaky_relu(m)*att, slope<1
        float c1 = fmaxf(m1, 0.2f * m1) * attv1;
        #pragma unroll
        for (int off = 32; off > 0; off >>= 1) {
            c0 += __shfl_xor(c0, off, 64);
            c1 += __shfl_xor(c1, off, 64);
        }
        if (c0 <= M0 && c1 <= M1) {               // wave-uniform fast path: no rescale
            float e0 = __expf(c0 - M0), e1 = __expf(c1 - M1);
            D0 += e0; D1 += e1;
            acc0 = fmaf(e0, xl0, acc0);
            acc1 = fmaf(e1, xl1, acc1);
        } else {
            float nm0 = fmaxf(M0, c0), nm1 = fmaxf(M1, c1);
            float s0 = __expf(M0 - nm0), s1 = __expf(M1 - nm1);
            float e0 = __expf(c0 - nm0), e1 = __expf(c1 - nm1);
            D0 = fmaf(D0, s0, e0); D1 = fmaf(D1, s1, e1);
            acc0 = acc0 * s0 + e0 * xl0;
            acc1 = acc1 * s1 + e1 * xl1;
            M0 = nm0; M1 = nm1;
        }
    }
    hpre[(size_t)d * HDV + L]      = acc0 / (D0 + 1e-16f) + cb[L];
    hpre[(size_t)d * HDV + 64 + L] = acc1 / (D1 + 1e-16f) + cb[64 + L];
}

// ---------------- BatchNorm ----------------

__global__ __launch_bounds__(256) void k_bn_stats(const float* __restrict__ hpre,
                                                  double* __restrict__ bnsum, double* __restrict__ bnsumsq) {
    int c = threadIdx.x & 127, half = threadIdx.x >> 7;
    int r0 = blockIdx.x * 250;
    double s = 0.0, q = 0.0;
    for (int r = r0 + half; r < r0 + 250; r += 2) {
        float v = hpre[(size_t)r * HDV + c];
        s += v;
        q += (double)v * (double)v;
    }
    __shared__ double ls[256], lq[256];
    ls[threadIdx.x] = s; lq[threadIdx.x] = q;
    __syncthreads();
    if (half == 0) {
        s += ls[threadIdx.x + 128];
        q += lq[threadIdx.x + 128];
        atomicAdd(&bnsum[c], s);
        atomicAdd(&bnsumsq[c], q);
    }
}

__global__ __launch_bounds__(256) void k_bn_apply(const float* __restrict__ hpre,
                                                  const double* __restrict__ bnsum, const double* __restrict__ bnsumsq,
                                                  const float* __restrict__ g, const float* __restrict__ bb,
                                                  float* __restrict__ act) {
    int idx = (blockIdx.x * 256 + threadIdx.x) * 4;
    if (idx >= NN * HDV) return;
    int c = idx & 127;
    float4 h = *(const float4*)&hpre[idx];
    float hv[4] = {h.x, h.y, h.z, h.w};
    float o[4];
    #pragma unroll
    for (int j = 0; j < 4; ++j) {
        int cc = c + j;
        double mu = bnsum[cc] * (1.0 / NN);
        double var = bnsumsq[cc] * (1.0 / NN) - mu * mu;
        float inv = (float)rsqrt(var + 1e-5);
        float xv = (hv[j] - (float)mu) * inv * g[cc] + bb[cc];
        o[j] = xv > 0.f ? xv : 0.01f * xv;
    }
    float4 v = {o[0], o[1], o[2], o[3]};
    *(float4*)&act[idx] = v;
}

// ---------------- pooling + MLP ----------------

__global__ void k_gbounds(const int* __restrict__ batch, int* __restrict__ gstart) {
    int g = threadIdx.x;
    if (g > NG) return;
    int lo = 0, hi = NN;
    while (lo < hi) {
        int mid = (lo + hi) >> 1;
        if (batch[mid] < g) lo = mid + 1; else hi = mid;
    }
    gstart[g] = lo;
}

__global__ __launch_bounds__(256) void k_pool2(const float* __restrict__ act, const int* __restrict__ gstart,
                                               float* __restrict__ pooled) {
    int g = blockIdx.x;
    int s = gstart[g], e = gstart[g + 1];
    int c = threadIdx.x & 127, half = threadIdx.x >> 7;
    float acc = 0.f;
    for (int r = s + half; r < e; r += 2) acc += act[(size_t)r * HDV + c];
    __shared__ float ls[256];
    ls[threadIdx.x] = acc;
    __syncthreads();
    if (half == 0) {
        float v = acc + ls[threadIdx.x + 128];
        int cntn = e - s;
        pooled[g * HDV + c] = v / (float)max(cntn, 1);
    }
}

__global__ __launch_bounds__(512) void k_mlp(const float* __restrict__ pooled,
                                             const float* __restrict__ fc1w, const float* __restrict__ fc1b,
                                             const float* __restrict__ fc2w, const float* __restrict__ fc2b,
                                             float* __restrict__ out) {
    __shared__ float pl[NG * HDV];   // 32 KB
    __shared__ float hh[NG * 64];    // 16 KB
    int t = threadIdx.x;
    for (int i = t; i < NG * HDV; i += 512) pl[i] = pooled[i];
    __syncthreads();
    for (int i = t; i < NG * 64; i += 512) {
        int g = i >> 6, c = i & 63;
        float s = fc1b[c];
        for (int k = 0; k < HDV; ++k) s += pl[g * HDV + k] * fc1w[k * 64 + c];
        hh[i] = s > 0.f ? s : 0.f;
    }
    __syncthreads();
    if (t < NG) {
        float s = fc2b[0];
        for (int k = 0; k < 64; ++k) s += hh[t * 64 + k] * fc2w[k];
        out[t] = s;
    }
}

// ---------------- launch ----------------

extern "C" void kernel_launch(void* const* d_in, const int* in_sizes, int n_in,
                              void* d_out, int out_size, void* d_ws, size_t ws_size,
                              hipStream_t stream) {
    const float* x = (const float*)d_in[0];
    const int* ei = (const int*)d_in[1];
    const int* src = ei;
    const int* dst = ei + NE;
    const float* ea = (const float*)d_in[2];
    const int* batch = (const int*)d_in[3];
    const float* fc1w = (const float*)d_in[25];
    const float* fc1b = (const float*)d_in[26];
    const float* fc2w = (const float*)d_in[27];
    const float* fc2b = (const float*)d_in[28];
    float* out = (float*)d_out;

    char* ws = (char*)d_ws;
    size_t off = 0;
    auto alloc = [&](size_t bytes) -> void* {
        void* p = ws + off;
        off = (off + bytes + 255) & ~(size_t)255;
        return p;
    };

    // zero region (memset every launch)
    int* cnt = (int*)alloc(NN * 4);
    double* bnsum = (double*)alloc(3 * HDV * 8);
    double* bnsumsq = (double*)alloc(3 * HDV * 8);
    size_t zero_bytes = off;

    int* rowptr = (int*)alloc((NN + 1) * 4);
    int* cursor = (int*)alloc(NN * 4);
    int* gstart = (int*)alloc((NG + 1) * 4);
    float* pooled = (float*)alloc(NG * HDV * 4);
    int* csr_src = (int*)alloc(((size_t)EF + 16) * 4);
    float* csr_ea = (float*)alloc(((size_t)EF * DEV + 16) * 4);
    float* XLb = (float*)alloc((size_t)NN * HDV * 4);
    float* XRb = (float*)alloc((size_t)NN * HDV * 4);
    float* hpre = (float*)alloc((size_t)NN * HDV * 4);
    float* actb = (float*)alloc((size_t)NN * HDV * 4);
    (void)ws_size; (void)in_sizes; (void)n_in; (void)out_size;

    hipMemsetAsync(d_ws, 0, zero_bytes, stream);

    k_count<<<(NE + 255) / 256, 256, 0, stream>>>(dst, cnt);
    k_scan<<<1, 1024, 0, stream>>>(cnt, rowptr);
    k_csr_init<<<(NN + 255) / 256, 256, 0, stream>>>(rowptr, cursor, csr_src);
    k_fill<<<(NE + 255) / 256, 256, 0, stream>>>(src, dst, ea, cursor, csr_src, csr_ea);
    k_loop_attr<<<(NN * DEV + 255) / 256, 256, 0, stream>>>(rowptr, csr_ea);
    k_gbounds<<<1, 128, 0, stream>>>(batch, gstart);

    const float* actp = x;
    int K = DINV;
    for (int L = 0; L < 3; ++L) {
        const float* wl = (const float*)d_in[4 + 7 * L + 0];
        const float* wr = (const float*)d_in[4 + 7 * L + 1];
        const float* we = (const float*)d_in[4 + 7 * L + 2];
        const float* a  = (const float*)d_in[4 + 7 * L + 3];
        const float* cb = (const float*)d_in[4 + 7 * L + 4];
        const float* g  = (const float*)d_in[4 + 7 * L + 5];
        const float* bb = (const float*)d_in[4 + 7 * L + 6];

        k_gemm<<<dim3(NN / 64, 4), 256, 0, stream>>>(actp, K, wl, wr, XLb, XRb);
        k_gat<<<NN / 4, 256, 0, stream>>>(XLb, XRb, rowptr, csr_src, csr_ea, we, a, cb, hpre);
        k_bn_stats<<<160, 256, 0, stream>>>(hpre, bnsum + (size_t)L * HDV, bnsumsq + (size_t)L * HDV);
        k_bn_apply<<<NN * HDV / 4 / 256, 256, 0, stream>>>(hpre, bnsum + (size_t)L * HDV, bnsumsq + (size_t)L * HDV, g, bb, actb);
        actp = actb;
        K = HDV;
    }

    k_pool2<<<NG, 256, 0, stream>>>(actb, gstart, pooled);
    k_mlp<<<1, 512, 0, stream>>>(pooled, fc1w, fc1b, fc2w, fc2b, out);
}

// Round 4
// 729.437 us; speedup vs baseline: 1.9584x; 1.1580x over previous
//
#include <hip/hip_runtime.h>
#include <math.h>

#define NN 40000
#define NE 640000
#define NG 64
#define DINV 64
#define HDV 128
#define DEV 16
#define EF (NE + NN)

// ---------------- DPP wave-64 sum (rocPRIM sequence), result uniform ----------------
template <int CTRL>
__device__ __forceinline__ float dpp_mov_f(float x) {
    return __builtin_bit_cast(float,
        __builtin_amdgcn_update_dpp(0, __builtin_bit_cast(int, x), CTRL, 0xf, 0xf, true));
}
__device__ __forceinline__ float wave_sum64(float x) {
    x += dpp_mov_f<0x111>(x);   // row_shr:1
    x += dpp_mov_f<0x112>(x);   // row_shr:2
    x += dpp_mov_f<0x114>(x);   // row_shr:4
    x += dpp_mov_f<0x118>(x);   // row_shr:8
    x += dpp_mov_f<0x142>(x);   // row_bcast:15
    x += dpp_mov_f<0x143>(x);   // row_bcast:31
    return __builtin_bit_cast(float, __builtin_amdgcn_readlane(__builtin_bit_cast(int, x), 63));
}

// ---------------- CSR construction ----------------

__global__ void k_count(const int* __restrict__ dst, int* __restrict__ cnt) {
    int e = blockIdx.x * 256 + threadIdx.x;
    if (e < NE) atomicAdd(&cnt[dst[e]], 1);
}

__global__ __launch_bounds__(1024) void k_scan(const int* __restrict__ cnt, int* __restrict__ rowptr) {
    const int C = 40;  // 1024*40 >= 40000
    int t = threadIdx.x;
    int start = t * C;
    int end = min(start + C, NN);
    int local = 0;
    for (int i = start; i < end; ++i) local += cnt[i] + 1;  // +1 self loop
    __shared__ int ssum[1024];
    ssum[t] = local;
    __syncthreads();
    for (int off = 1; off < 1024; off <<= 1) {
        int v = (t >= off) ? ssum[t - off] : 0;
        __syncthreads();
        ssum[t] += v;
        __syncthreads();
    }
    int running = (t == 0) ? 0 : ssum[t - 1];
    for (int i = start; i < end; ++i) {
        rowptr[i] = running;
        running += cnt[i] + 1;
    }
    if (end == NN && start < NN) rowptr[NN] = running;
}

__global__ void k_csr_init(const int* __restrict__ rowptr, int* __restrict__ cursor,
                           int* __restrict__ csr_src) {
    int n = blockIdx.x * 256 + threadIdx.x;
    if (n < NN) {
        cursor[n] = rowptr[n];
        csr_src[rowptr[n + 1] - 1] = n;   // self-loop in last slot
    }
}

// fill CSR adjacency AND edge attrs in CSR order
__global__ void k_fill(const int* __restrict__ src, const int* __restrict__ dst,
                       const float* __restrict__ edge_attr,
                       int* __restrict__ cursor, int* __restrict__ csr_src, float* __restrict__ csr_ea) {
    int e = blockIdx.x * 256 + threadIdx.x;
    if (e < NE) {
        int d = dst[e];
        int p = atomicAdd(&cursor[d], 1);
        csr_src[p] = src[e];
        const float4* s4 = (const float4*)&edge_attr[(size_t)e * DEV];
        float4* d4 = (float4*)&csr_ea[(size_t)p * DEV];
        d4[0] = s4[0]; d4[1] = s4[1]; d4[2] = s4[2]; d4[3] = s4[3];
    }
}

// self-loop attr = mean over incoming original edges' attrs (0 if none), written in place
__global__ void k_loop_attr(const int* __restrict__ rowptr, float* __restrict__ csr_ea) {
    int tid = blockIdx.x * 256 + threadIdx.x;
    int n = tid >> 4, k = tid & 15;
    if (n >= NN) return;
    int s = rowptr[n], e = rowptr[n + 1] - 1;  // exclude self loop slot
    float acc = 0.f;
    for (int i = s; i < e; ++i) acc += csr_ea[(size_t)i * DEV + k];
    csr_ea[(size_t)e * DEV + k] = acc / (float)max(e - s, 1);
}

// ---------------- dense transforms: XL = A@Wl, XR = A@Wr ----------------
// 128x128 tile, 8x8 per-thread register blocking. grid (ceil(NN/128), 2).
__global__ __launch_bounds__(256) void k_gemm(const float* __restrict__ A, int K,
                                              const float* __restrict__ Wl, const float* __restrict__ Wr,
                                              float* __restrict__ XL, float* __restrict__ XR) {
    __shared__ float As[8][128];
    __shared__ float Bs[8][128];
    int t = threadIdx.x;
    int rb = blockIdx.x * 128;
    const float* __restrict__ Bg = blockIdx.y ? Wr : Wl;
    float* __restrict__ Xout = blockIdx.y ? XR : XL;
    int tx = t & 15, ty = t >> 4;
    int lr_ = t >> 1, lk = (t & 1) * 4;     // A: thread loads float4 (row=lr_, k=lk..lk+3)
    int bk = t >> 5, bc = (t & 31) * 4;     // B: thread loads float4 (k=bk, col=bc..bc+3)
    float acc[8][8] = {};
    for (int k0 = 0; k0 < K; k0 += 8) {
        float4 av = (rb + lr_ < NN) ? *(const float4*)&A[(size_t)(rb + lr_) * K + k0 + lk]
                                    : float4{0.f, 0.f, 0.f, 0.f};
        float4 bv = *(const float4*)&Bg[(size_t)(k0 + bk) * HDV + bc];
        __syncthreads();   // previous-iter tile reads done
        As[lk + 0][lr_] = av.x; As[lk + 1][lr_] = av.y; As[lk + 2][lr_] = av.z; As[lk + 3][lr_] = av.w;
        *(float4*)&Bs[bk][bc] = bv;
        __syncthreads();
        #pragma unroll
        for (int kk = 0; kk < 8; ++kk) {
            float a8[8], b8[8];
            *(float4*)&a8[0] = *(const float4*)&As[kk][ty * 8];
            *(float4*)&a8[4] = *(const float4*)&As[kk][ty * 8 + 4];
            *(float4*)&b8[0] = *(const float4*)&Bs[kk][tx * 8];
            *(float4*)&b8[4] = *(const float4*)&Bs[kk][tx * 8 + 4];
            #pragma unroll
            for (int ii = 0; ii < 8; ++ii)
                #pragma unroll
                for (int jj = 0; jj < 8; ++jj)
                    acc[ii][jj] = fmaf(a8[ii], b8[jj], acc[ii][jj]);
        }
    }
    #pragma unroll
    for (int ii = 0; ii < 8; ++ii) {
        int row = rb + ty * 8 + ii;
        if (row < NN) {
            float4 v0 = {acc[ii][0], acc[ii][1], acc[ii][2], acc[ii][3]};
            float4 v1 = {acc[ii][4], acc[ii][5], acc[ii][6], acc[ii][7]};
            *(float4*)&Xout[(size_t)row * HDV + tx * 8] = v0;
            *(float4*)&Xout[(size_t)row * HDV + tx * 8 + 4] = v1;
        }
    }
}

// ---------------- GATv2 per-node softmax aggregation ----------------
// one wave per node; lane L owns channels L (head0) and 64+L (head1).
// No max-subtraction: scores are O(few), exp(s) is fp32-safe and exp(s)/sum == ref softmax.
__device__ __forceinline__ void edge_op(int s, const float* __restrict__ eap,
                                        const float* __restrict__ XL, int L,
                                        const float* __restrict__ rwe0, const float* __restrict__ rwe1,
                                        float xr0, float xr1, float attv0, float attv1,
                                        float& D0, float& D1, float& A0, float& A1) {
    float xl0 = XL[(size_t)s * HDV + L];
    float xl1 = XL[(size_t)s * HDV + 64 + L];
    float e00 = 0.f, e01 = 0.f, e10 = 0.f, e11 = 0.f;
    #pragma unroll
    for (int k = 0; k < DEV; k += 2) {
        e00 = fmaf(eap[k],     rwe0[k],     e00);
        e10 = fmaf(eap[k],     rwe1[k],     e10);
        e01 = fmaf(eap[k + 1], rwe0[k + 1], e01);
        e11 = fmaf(eap[k + 1], rwe1[k + 1], e11);
    }
    float m0 = xl0 + xr0 + (e00 + e01);
    float m1 = xl1 + xr1 + (e10 + e11);
    float c0 = fmaxf(m0, 0.2f * m0) * attv0;   // leaky_relu * att
    float c1 = fmaxf(m1, 0.2f * m1) * attv1;
    float s0 = wave_sum64(c0);
    float s1 = wave_sum64(c1);
    float e0 = __expf(s0), e1 = __expf(s1);
    D0 += e0; D1 += e1;
    A0 = fmaf(e0, xl0, A0);
    A1 = fmaf(e1, xl1, A1);
}

__global__ __launch_bounds__(256) void k_gat(const float* __restrict__ XL, const float* __restrict__ XR,
                                             const int* __restrict__ rowptr, const int* __restrict__ csr_src,
                                             const float* __restrict__ csr_ea,
                                             const float* __restrict__ we, const float* __restrict__ att,
                                             const float* __restrict__ cb, float* __restrict__ hpre) {
    int t = threadIdx.x;
    int L = t & 63;
    int d = __builtin_amdgcn_readfirstlane(blockIdx.x * 4 + (t >> 6));
    float rwe0[DEV], rwe1[DEV];
    #pragma unroll
    for (int k = 0; k < DEV; ++k) {
        rwe0[k] = we[k * HDV + L];
        rwe1[k] = we[k * HDV + 64 + L];
    }
    float attv0 = att[L], attv1 = att[64 + L];
    float xr0 = XR[(size_t)d * HDV + L];
    float xr1 = XR[(size_t)d * HDV + 64 + L];
    int istart = rowptr[d], iend = rowptr[d + 1];
    float D0a = 0.f, D1a = 0.f, D0b = 0.f, D1b = 0.f;
    float a0a = 0.f, a1a = 0.f, a0b = 0.f, a1b = 0.f;
    int i = istart;
    for (; i + 2 <= iend; i += 2) {
        int sA = csr_src[i], sB = csr_src[i + 1];
        const float* eA = csr_ea + (size_t)i * DEV;
        edge_op(sA, eA,       XL, L, rwe0, rwe1, xr0, xr1, attv0, attv1, D0a, D1a, a0a, a1a);
        edge_op(sB, eA + DEV, XL, L, rwe0, rwe1, xr0, xr1, attv0, attv1, D0b, D1b, a0b, a1b);
    }
    if (i < iend) {
        int sA = csr_src[i];
        edge_op(sA, csr_ea + (size_t)i * DEV, XL, L, rwe0, rwe1, xr0, xr1, attv0, attv1, D0a, D1a, a0a, a1a);
    }
    float D0 = D0a + D0b, D1 = D1a + D1b;
    float acc0 = a0a + a0b, acc1 = a1a + a1b;
    hpre[(size_t)d * HDV + L]      = acc0 / (D0 + 1e-16f) + cb[L];
    hpre[(size_t)d * HDV + 64 + L] = acc1 / (D1 + 1e-16f) + cb[64 + L];
}

// ---------------- BatchNorm ----------------

__global__ __launch_bounds__(256) void k_bn_stats(const float* __restrict__ hpre,
                                                  double* __restrict__ bnsum, double* __restrict__ bnsumsq) {
    int c = threadIdx.x & 127, half = threadIdx.x >> 7;
    int r0 = blockIdx.x * 250;
    double s = 0.0, q = 0.0;
    for (int r = r0 + half; r < r0 + 250; r += 2) {
        float v = hpre[(size_t)r * HDV + c];
        s += v;
        q += (double)v * (double)v;
    }
    __shared__ double ls[256], lq[256];
    ls[threadIdx.x] = s; lq[threadIdx.x] = q;
    __syncthreads();
    if (half == 0) {
        s += ls[threadIdx.x + 128];
        q += lq[threadIdx.x + 128];
        atomicAdd(&bnsum[c], s);
        atomicAdd(&bnsumsq[c], q);
    }
}

__global__ __launch_bounds__(256) void k_bn_apply(const float* __restrict__ hpre,
                                                  const double* __restrict__ bnsum, const double* __restrict__ bnsumsq,
                                                  const float* __restrict__ g, const float* __restrict__ bb,
                                                  float* __restrict__ act) {
    int idx = (blockIdx.x * 256 + threadIdx.x) * 4;
    if (idx >= NN * HDV) return;
    int c = idx & 127;
    float4 h = *(const float4*)&hpre[idx];
    float hv[4] = {h.x, h.y, h.z, h.w};
    float o[4];
    #pragma unroll
    for (int j = 0; j < 4; ++j) {
        int cc = c + j;
        double mu = bnsum[cc] * (1.0 / NN);
        double var = bnsumsq[cc] * (1.0 / NN) - mu * mu;
        float inv = (float)rsqrt(var + 1e-5);
        float xv = (hv[j] - (float)mu) * inv * g[cc] + bb[cc];
        o[j] = xv > 0.f ? xv : 0.01f * xv;
    }
    float4 v = {o[0], o[1], o[2], o[3]};
    *(float4*)&act[idx] = v;
}

// ---------------- pooling + MLP ----------------

__global__ void k_gbounds(const int* __restrict__ batch, int* __restrict__ gstart) {
    int g = threadIdx.x;
    if (g > NG) return;
    int lo = 0, hi = NN;
    while (lo < hi) {
        int mid = (lo + hi) >> 1;
        if (batch[mid] < g) lo = mid + 1; else hi = mid;
    }
    gstart[g] = lo;
}

__global__ __launch_bounds__(256) void k_pool2(const float* __restrict__ act, const int* __restrict__ gstart,
                                               float* __restrict__ pooled) {
    int g = blockIdx.x;
    int s = gstart[g], e = gstart[g + 1];
    int c = threadIdx.x & 127, half = threadIdx.x >> 7;
    float acc = 0.f;
    for (int r = s + half; r < e; r += 2) acc += act[(size_t)r * HDV + c];
    __shared__ float ls[256];
    ls[threadIdx.x] = acc;
    __syncthreads();
    if (half == 0) {
        float v = acc + ls[threadIdx.x + 128];
        int cntn = e - s;
        pooled[g * HDV + c] = v / (float)max(cntn, 1);
    }
}

__global__ __launch_bounds__(512) void k_mlp(const float* __restrict__ pooled,
                                             const float* __restrict__ fc1w, const float* __restrict__ fc1b,
                                             const float* __restrict__ fc2w, const float* __restrict__ fc2b,
                                             float* __restrict__ out) {
    __shared__ float pl[NG * HDV];   // 32 KB
    __shared__ float hh[NG * 64];    // 16 KB
    int t = threadIdx.x;
    for (int i = t; i < NG * HDV; i += 512) pl[i] = pooled[i];
    __syncthreads();
    for (int i = t; i < NG * 64; i += 512) {
        int g = i >> 6, c = i & 63;
        float s = fc1b[c];
        for (int k = 0; k < HDV; ++k) s += pl[g * HDV + k] * fc1w[k * 64 + c];
        hh[i] = s > 0.f ? s : 0.f;
    }
    __syncthreads();
    if (t < NG) {
        float s = fc2b[0];
        for (int k = 0; k < 64; ++k) s += hh[t * 64 + k] * fc2w[k];
        out[t] = s;
    }
}

// ---------------- launch ----------------

extern "C" void kernel_launch(void* const* d_in, const int* in_sizes, int n_in,
                              void* d_out, int out_size, void* d_ws, size_t ws_size,
                              hipStream_t stream) {
    const float* x = (const float*)d_in[0];
    const int* ei = (const int*)d_in[1];
    const int* src = ei;
    const int* dst = ei + NE;
    const float* ea = (const float*)d_in[2];
    const int* batch = (const int*)d_in[3];
    const float* fc1w = (const float*)d_in[25];
    const float* fc1b = (const float*)d_in[26];
    const float* fc2w = (const float*)d_in[27];
    const float* fc2b = (const float*)d_in[28];
    float* out = (float*)d_out;

    char* ws = (char*)d_ws;
    size_t off = 0;
    auto alloc = [&](size_t bytes) -> void* {
        void* p = ws + off;
        off = (off + bytes + 255) & ~(size_t)255;
        return p;
    };

    // zero region (memset every launch)
    int* cnt = (int*)alloc(NN * 4);
    double* bnsum = (double*)alloc(3 * HDV * 8);
    double* bnsumsq = (double*)alloc(3 * HDV * 8);
    size_t zero_bytes = off;

    int* rowptr = (int*)alloc((NN + 1) * 4);
    int* cursor = (int*)alloc(NN * 4);
    int* gstart = (int*)alloc((NG + 1) * 4);
    float* pooled = (float*)alloc(NG * HDV * 4);
    int* csr_src = (int*)alloc(((size_t)EF + 16) * 4);
    float* csr_ea = (float*)alloc(((size_t)EF * DEV + 16) * 4);
    float* XLb = (float*)alloc((size_t)NN * HDV * 4);
    float* XRb = (float*)alloc((size_t)NN * HDV * 4);
    float* hpre = (float*)alloc((size_t)NN * HDV * 4);
    float* actb = (float*)alloc((size_t)NN * HDV * 4);
    (void)ws_size; (void)in_sizes; (void)n_in; (void)out_size;

    hipMemsetAsync(d_ws, 0, zero_bytes, stream);

    k_count<<<(NE + 255) / 256, 256, 0, stream>>>(dst, cnt);
    k_scan<<<1, 1024, 0, stream>>>(cnt, rowptr);
    k_csr_init<<<(NN + 255) / 256, 256, 0, stream>>>(rowptr, cursor, csr_src);
    k_fill<<<(NE + 255) / 256, 256, 0, stream>>>(src, dst, ea, cursor, csr_src, csr_ea);
    k_loop_attr<<<(NN * DEV + 255) / 256, 256, 0, stream>>>(rowptr, csr_ea);
    k_gbounds<<<1, 128, 0, stream>>>(batch, gstart);

    const float* actp = x;
    int K = DINV;
    for (int L = 0; L < 3; ++L) {
        const float* wl = (const float*)d_in[4 + 7 * L + 0];
        const float* wr = (const float*)d_in[4 + 7 * L + 1];
        const float* we = (const float*)d_in[4 + 7 * L + 2];
        const float* a  = (const float*)d_in[4 + 7 * L + 3];
        const float* cb = (const float*)d_in[4 + 7 * L + 4];
        const float* g  = (const float*)d_in[4 + 7 * L + 5];
        const float* bb = (const float*)d_in[4 + 7 * L + 6];

        k_gemm<<<dim3((NN + 127) / 128, 2), 256, 0, stream>>>(actp, K, wl, wr, XLb, XRb);
        k_gat<<<NN / 4, 256, 0, stream>>>(XLb, XRb, rowptr, csr_src, csr_ea, we, a, cb, hpre);
        k_bn_stats<<<160, 256, 0, stream>>>(hpre, bnsum + (size_t)L * HDV, bnsumsq + (size_t)L * HDV);
        k_bn_apply<<<NN * HDV / 4 / 256, 256, 0, stream>>>(hpre, bnsum + (size_t)L * HDV, bnsumsq + (size_t)L * HDV, g, bb, actb);
        actp = actb;
        K = HDV;
    }

    k_pool2<<<NG, 256, 0, stream>>>(actb, gstart, pooled);
    k_mlp<<<1, 512, 0, stream>>>(pooled, fc1w, fc1b, fc2w, fc2b, out);
}